// Round 14
// baseline (130.762 us; speedup 1.0000x reference)
//
#include <hip/hip_runtime.h>

typedef short bf16x8 __attribute__((ext_vector_type(8)));
typedef float f32x16 __attribute__((ext_vector_type(16)));

#define BIG_F 1e10f
constexpr int B = 16;
constexpr int N = 4096;
constexpr int ROWS = 256;        // query rows per block
constexpr int COLS = 512;        // set cols per block
constexpr int NRB = N / ROWS;    // 16
constexpr int NCB = N / COLS;    // 8
constexpr int NCC = COLS / 32;   // 16 col chunks of 32

// truncating bf16 hi/lo split: v ~= hi + lo with |v-hi-lo| <= 2^-16 |v|
__device__ __forceinline__ void split(float v, unsigned short& h, unsigned short& l) {
    unsigned hb = __float_as_uint(v) & 0xFFFF0000u;
    h = (unsigned short)(hb >> 16);
    float r = v - __uint_as_float(hb);
    l = (unsigned short)(__float_as_uint(r) >> 16);
}

// P[n,m] = qq[n] + ss[m] - 2 q_n . s_m (+BIG on masked rows/cols) via
// mfma_f32_32x32x16_bf16, K=16 fully used (R13-verified layouts):
//   A: lane L holds A[m=L&31][k=(L>>5)*8+j]; B: lane L holds B[k=(L>>5)*8+j][n=L&31]
//   C/D: col=L&31, row=(reg&3)+8*(reg>>2)+4*(L>>5)
// ROW-MIN ONLY kernel: direction 2 handled by a second grid z-slice with
// q/s roles swapped (col-min of P == row-min of P^T). No cross-lane ops,
// no LDS writes, no divergence inside the cc loop.
__global__ __launch_bounds__(256) void chamfer_mfma(
    const float* __restrict__ x, const float* __restrict__ y,
    const int* __restrict__ mask,
    float* __restrict__ rowpart,   // [2][B][NCB][N] exclusive slots (no init)
    float* __restrict__ out)
{
    const int rb  = blockIdx.x & 15;   // row-block 0..15
    const int cb  = blockIdx.x >> 4;   // col-block 0..7
    const int b   = blockIdx.y;
    const int dir = blockIdx.z;
    const int t   = threadIdx.x;

    const float* Q = (dir == 0 ? x : y) + (size_t)b * 3 * N;  // queries (rows)
    const float* S = (dir == 0 ? y : x) + (size_t)b * 3 * N;  // sets (cols)

    __shared__ unsigned short Apack[ROWS * 16];  // 8 KB
    __shared__ unsigned short Bpack[COLS * 16];  // 16 KB

    if (blockIdx.x == 0 && b == 0 && dir == 0 && t == 0) out[0] = 0.0f;

    const unsigned short one = 0x3F80;  // bf16 1.0

    // ---- pack A: 256 query points, one per thread ----
    {
        int n = rb * ROWS + t;
        float q0 = Q[n], q1 = Q[N + n], q2 = Q[2 * N + n];
        float qq = fmaf(q2, q2, fmaf(q1, q1, q0 * q0));
        unsigned short ah0, al0, ah1, al1, ah2, al2, qh, ql;
        split(-2.0f * q0, ah0, al0);
        split(-2.0f * q1, ah1, al1);
        split(-2.0f * q2, ah2, al2);
        split(qq, qh, ql);
        unsigned short* p = &Apack[t * 16];
        p[0] = ah0; p[1] = ah1; p[2] = ah2; p[3] = ah0; p[4] = ah1; p[5] = ah2;
        p[6] = al0; p[7] = al1; p[8] = al2; p[9] = al0; p[10] = al1; p[11] = al2;
        p[12] = qh; p[13] = ql; p[14] = one; p[15] = one;
    }
    // ---- pack B: 512 set points, two per thread ----
#pragma unroll
    for (int i = 0; i < 2; ++i) {
        int c = t + i * 256;
        int m = cb * COLS + c;
        float s0 = S[m], s1 = S[N + m], s2 = S[2 * N + m];
        float madd = mask[b * N + m] ? 0.0f : BIG_F;
        float ss = fmaf(s2, s2, fmaf(s1, s1, s0 * s0)) + madd;
        unsigned short sh0, sl0, sh1, sl1, sh2, sl2, th, tl;
        split(s0, sh0, sl0);
        split(s1, sh1, sl1);
        split(s2, sh2, sl2);
        split(ss, th, tl);
        unsigned short* p = &Bpack[c * 16];
        p[0] = sh0; p[1] = sh1; p[2] = sh2; p[3] = sl0; p[4] = sl1; p[5] = sl2;
        p[6] = sh0; p[7] = sh1; p[8] = sh2; p[9] = sl0; p[10] = sl1; p[11] = sl2;
        p[12] = one; p[13] = one; p[14] = th; p[15] = tl;
    }
    __syncthreads();

    const int w  = t >> 6;    // wave 0..3 (owns rows w*64..w*64+63)
    const int L  = t & 63;
    const int h  = L >> 5;    // k-half 0..1
    const int ln = L & 31;

    bf16x8 afr[2];
#pragma unroll
    for (int s = 0; s < 2; ++s)
        afr[s] = *(const bf16x8*)&Apack[(w * 64 + s * 32 + ln) * 16 + h * 8];

    float rm[2][16];
#pragma unroll
    for (int s = 0; s < 2; ++s)
#pragma unroll
        for (int i = 0; i < 16; ++i) rm[s][i] = 1e30f;

    bf16x8 nbf = *(const bf16x8*)&Bpack[ln * 16 + h * 8];

    for (int cc = 0; cc < NCC; ++cc) {
        bf16x8 bf = nbf;
        if (cc + 1 < NCC)
            nbf = *(const bf16x8*)&Bpack[((cc + 1) * 32 + ln) * 16 + h * 8];

        f32x16 z = {};
        f32x16 C0 = __builtin_amdgcn_mfma_f32_32x32x16_bf16(afr[0], bf, z, 0, 0, 0);
        f32x16 C1 = __builtin_amdgcn_mfma_f32_32x32x16_bf16(afr[1], bf, z, 0, 0, 0);
#pragma unroll
        for (int i = 0; i < 16; ++i) {
            rm[0][i] = fminf(rm[0][i], C0[i]);
            rm[1][i] = fminf(rm[1][i], C1[i]);
        }
    }

    // epilogue: reduce row-mins across the 32 col-lanes (once per block)
#pragma unroll
    for (int off = 1; off <= 16; off <<= 1)
#pragma unroll
        for (int s = 0; s < 2; ++s)
#pragma unroll
            for (int i = 0; i < 16; ++i)
                rm[s][i] = fminf(rm[s][i], __shfl_xor(rm[s][i], off));
    if (ln == 0) {
        float* rp = rowpart + (((size_t)dir * B + b) * NCB + cb) * N
                  + rb * ROWS + w * 64;
#pragma unroll
        for (int s = 0; s < 2; ++s)
#pragma unroll
            for (int i = 0; i < 16; ++i)
                rp[s * 32 + (i & 3) + 8 * (i >> 2) + 4 * h] = rm[s][i];
    }
}

__global__ __launch_bounds__(256) void finalize_kernel(
    const int* __restrict__ mask, const float* __restrict__ rowpart,
    float* __restrict__ out)
{
    const int b   = blockIdx.x & 15;
    const int dir = (blockIdx.x >> 4) & 1;
    const int q   = blockIdx.x >> 5;   // quarter 0..3
    const int t   = threadIdx.x;
    const int* mrow = mask + b * N;

    int cnt = 0;
    for (int i = t; i < N / 4; i += 256) {
        int4 mk = ((const int4*)mrow)[i];
        cnt += mk.x + mk.y + mk.z + mk.w;
    }

    const float* base = rowpart + ((size_t)dir * B + b) * NCB * N;

    const int p0 = q * 1024 + t * 4;
    float4 mn = *(const float4*)(base + p0);
#pragma unroll
    for (int pb = 1; pb < NCB; ++pb) {
        float4 v = *(const float4*)(base + (size_t)pb * N + p0);
        mn.x = fminf(mn.x, v.x); mn.y = fminf(mn.y, v.y);
        mn.z = fminf(mn.z, v.z); mn.w = fminf(mn.w, v.w);
    }
    int4 mk = *(const int4*)(mrow + p0);
    float s = (mk.x ? mn.x : 0.f) + (mk.y ? mn.y : 0.f)
            + (mk.z ? mn.z : 0.f) + (mk.w ? mn.w : 0.f);

    for (int off = 32; off > 0; off >>= 1) {
        s   += __shfl_down(s, off);
        cnt += __shfl_down(cnt, off);
    }
    __shared__ float rs[4];
    __shared__ int   rc[4];
    const int wv = t >> 6;
    if ((t & 63) == 0) { rs[wv] = s; rc[wv] = cnt; }
    __syncthreads();
    if (t == 0) {
        float S = rs[0] + rs[1] + rs[2] + rs[3];
        float C = (float)(rc[0] + rc[1] + rc[2] + rc[3]);
        atomicAdd(out, (S / C) * (1.0f / 16.0f));
    }
}

extern "C" void kernel_launch(void* const* d_in, const int* in_sizes, int n_in,
                              void* d_out, int out_size, void* d_ws, size_t ws_size,
                              hipStream_t stream) {
    const float* x    = (const float*)d_in[0];
    const float* y    = (const float*)d_in[1];
    const int*   mask = (const int*)d_in[2];

    float* rowpart = (float*)d_ws;  // 2*B*NCB*N floats = 4 MB

    chamfer_mfma<<<dim3(NRB * NCB, B, 2), 256, 0, stream>>>(
        x, y, mask, rowpart, (float*)d_out);
    finalize_kernel<<<dim3(128), 256, 0, stream>>>(
        mask, rowpart, (float*)d_out);
}